// Round 14
// baseline (376.409 us; speedup 1.0000x reference)
//
#include <hip/hip_runtime.h>
#include <hip/hip_bf16.h>
#include <stdint.h>

// HaloWindowAttention: B=512,C=128,H=W=16, WSH=24 -> 1 window/batch, 576 tokens,
// 4 heads x 32 dim, q = flat tokens [100,356), out [B,C,16,16] f32.
//
// Round-14: fused qkv+attn per (b,head) built ONLY from byte-proven pieces:
//  - xt global A-frags + reflect + weight B-frags + D-store pattern  [R13-proven]
//  - K/V staged via token-major OBK/OBV then R7's exact restage code [R7-proven]
//  - APH = R7 attention compute verbatim                             [R7-proven]
// Serial per-chunk sync with __syncthreads(); APH(c)∥GPH(c+1) share an interval.
// ws (u16): wp[16384] | wq[49152] | xt[16.8M] | ao[16.8M]  (~67.2 MB)

typedef short bf16x8 __attribute__((ext_vector_type(8)));
typedef float f32x4 __attribute__((ext_vector_type(4)));

__device__ __forceinline__ unsigned short f2bf(float f) {
  unsigned int u = __builtin_bit_cast(unsigned int, f);
  u += 0x7fffu + ((u >> 16) & 1u);
  return (unsigned short)(u >> 16);
}

__device__ __forceinline__ unsigned int cvt_pk_bf16(float lo, float hi) {
  unsigned int r;
  asm("v_cvt_pk_bf16_f32 %0, %1, %2" : "=v"(r) : "v"(lo), "v"(hi));
  return r;
}

__device__ __forceinline__ f32x4 mfma_16x16x32(bf16x8 a, bf16x8 b, f32x4 c) {
  return __builtin_amdgcn_mfma_f32_16x16x32_bf16(a, b, c, 0, 0, 0);
}

// LDS-only barrier (proven in xt/proj; fused uses __syncthreads).
__device__ __forceinline__ void bar_lds() {
  asm volatile("s_waitcnt lgkmcnt(0)\n\ts_barrier" ::: "memory");
}

__device__ __forceinline__ int reflect_s(int tg) {
  int ph = tg / 24;
  int pw = tg - ph * 24;
  int hh = ph - 4; hh = (hh < 0) ? -hh : ((hh > 15) ? 30 - hh : hh);
  int wc = pw - 4; wc = (wc < 0) ? -wc : ((wc > 15) ? 30 - wc : wc);
  return hh * 16 + wc;
}

// ---------------- kernel 0: weights f32 -> bf16 ----------------
__global__ void wcvt(const float* __restrict__ qkv_w, const float* __restrict__ proj_w,
                     unsigned short* __restrict__ wq, unsigned short* __restrict__ wp) {
  int i = blockIdx.x * 256 + threadIdx.x;
  if (i < 49152) wq[i] = f2bf(qkv_w[i]);
  if (i < 16384) wp[i] = f2bf(proj_w[i]);
}

// ---------------- kernel 1: x [C][S] f32 -> xT [S][C] bf16 ----------------
__global__ __launch_bounds__(256) void xt_kernel(const float* __restrict__ x,
                                                 unsigned short* __restrict__ xt) {
  __shared__ __align__(16) unsigned int XS[256 * 64];
  const int b = blockIdx.x, tid = threadIdx.x;
  const float* xb = x + (size_t)b * 32768;
  #pragma unroll 4
  for (int it = 0; it < 64; ++it) {
    float f0 = xb[(2 * it) * 256 + tid];
    float f1 = xb[(2 * it + 1) * 256 + tid];
    XS[tid * 64 + (it ^ ((tid & 7) << 2))] =
        (unsigned int)f2bf(f0) | ((unsigned int)f2bf(f1) << 16);
  }
  bar_lds();
  unsigned int* xtd = (unsigned int*)xt + (size_t)b * 16384;  // 256 s * 64 dwords
  #pragma unroll
  for (int it = 0; it < 4; ++it) {
    int s = it * 64 + (tid >> 2);
    int cg = (tid & 3) * 4;
    #pragma unroll
    for (int m = 0; m < 4; ++m) {
      uint4 v = *(const uint4*)&XS[s * 64 + (((cg + m) ^ (s & 7)) << 2)];
      *(uint4*)&xtd[s * 64 + (cg + m) * 4] = v;
    }
  }
}

// ---------------- kernel 2: FUSED qkv-GEMM + flash attention per (b, head) ----------------
// grid = 2048: xcd = bid&7, slot = bid>>3, b = xcd*64 + (slot&63), h = slot>>6
// -> each XCD serves 64 batches (2 MB xt, L2-resident) and all 4 heads.
// LDS (u16 offsets): QC[0,10240) | OBK[10240,17920) | OBV[17920,25600) |
//   KF(u32)[25600,31744) | VT[31744,38144)  = 76,288 B -> 2 blocks/CU.
__global__ __launch_bounds__(256) void fused_kernel(
    const unsigned short* __restrict__ xt, const unsigned short* __restrict__ wq,
    const float* __restrict__ qkv_b, unsigned short* __restrict__ ao) {
  __shared__ __align__(16) unsigned short POOL[38144];
  unsigned short* QC = POOL;                    // [256][40] token-major q
  unsigned short* OBK = POOL + 10240;           // [192][40] token-major k chunk
  unsigned short* OBV = POOL + 17920;           // [192][40] token-major v chunk
  unsigned int* KF = (unsigned int*)(POOL + 25600);  // [4][192][4] u32 frag-major
  unsigned short* VT = POOL + 31744;            // [32][200] phys-permuted V^T

  const int bid = blockIdx.x;
  const int slot = bid >> 3;
  const int b = (bid & 7) * 64 + (slot & 63);
  const int h = slot >> 6;
  const int tid = threadIdx.x;
  const int lane = tid & 63;
  const int wid = tid >> 6;   // 0..3
  const int g = lane >> 4;
  const int r16 = lane & 15;
  const int qb = wid * 64;

  const unsigned int* xtd = (const unsigned int*)xt + (size_t)b * 16384;
  const float KE = 0.17677669529663687f * 1.4426950408889634f;  // SCALE*log2(e)

  // ---- q-phase: wave computes its 64 q-rows x 32 head-cols -> QC [R13 D-store pattern] ----
  {
    f32x4 qacc[4][2];
    #pragma unroll
    for (int mt = 0; mt < 4; ++mt)
      #pragma unroll
      for (int nt = 0; nt < 2; ++nt) qacc[mt][nt] = f32x4{0.f, 0.f, 0.f, 0.f};
    #pragma unroll
    for (int kt = 0; kt < 4; ++kt) {
      bf16x8 Bf[2];
      #pragma unroll
      for (int nt = 0; nt < 2; ++nt)
        Bf[nt] = __builtin_bit_cast(
            bf16x8, *(const uint4*)(wq + (h * 32 + nt * 16 + r16) * 128 + kt * 32 + g * 8));
      #pragma unroll
      for (int mt = 0; mt < 4; ++mt) {
        int sv = reflect_s(100 + qb + mt * 16 + r16);
        bf16x8 A = __builtin_bit_cast(bf16x8, *(const uint4*)&xtd[sv * 64 + kt * 16 + g * 4]);
        #pragma unroll
        for (int nt = 0; nt < 2; ++nt) qacc[mt][nt] = mfma_16x16x32(A, Bf[nt], qacc[mt][nt]);
      }
    }
    #pragma unroll
    for (int nt = 0; nt < 2; ++nt) {
      float bv = qkv_b[h * 32 + nt * 16 + r16];
      #pragma unroll
      for (int mt = 0; mt < 4; ++mt)
        #pragma unroll
        for (int rr = 0; rr < 4; ++rr)
          QC[(qb + mt * 16 + 4 * g + rr) * 40 + nt * 16 + r16] = f2bf(qacc[mt][nt][rr] + bv);
    }
  }
  __syncthreads();
  bf16x8 qf[4];
  #pragma unroll
  for (int qnt = 0; qnt < 4; ++qnt)
    qf[qnt] = __builtin_bit_cast(bf16x8, *(const uint4*)&QC[(qb + qnt * 16 + r16) * 40 + g * 8]);

  float ls[4] = {0.f, 0.f, 0.f, 0.f};
  f32x4 oa[2][4];
  #pragma unroll
  for (int i = 0; i < 2; ++i)
    #pragma unroll
    for (int j = 0; j < 4; ++j) oa[i][j] = f32x4{0.f, 0.f, 0.f, 0.f};

  // GPH(c): K/V GEMM for chunk c -> token-major OBK/OBV [R13 D-store pattern]
  auto GPH = [&](int c) {
    f32x4 acc[3][4];
    #pragma unroll
    for (int m = 0; m < 3; ++m)
      #pragma unroll
      for (int j = 0; j < 4; ++j) acc[m][j] = f32x4{0.f, 0.f, 0.f, 0.f};
    #pragma unroll
    for (int kt = 0; kt < 4; ++kt) {
      bf16x8 Bf[4];
      #pragma unroll
      for (int j = 0; j < 4; ++j) {
        int n_abs = (1 + (j >> 1)) * 128 + h * 32 + (j & 1) * 16 + r16;
        Bf[j] = __builtin_bit_cast(bf16x8, *(const uint4*)(wq + n_abs * 128 + kt * 32 + g * 8));
      }
      #pragma unroll
      for (int m = 0; m < 3; ++m) {
        int sv = reflect_s(c * 192 + (wid * 3 + m) * 16 + r16);
        bf16x8 A = __builtin_bit_cast(bf16x8, *(const uint4*)&xtd[sv * 64 + kt * 16 + g * 4]);
        #pragma unroll
        for (int j = 0; j < 4; ++j) acc[m][j] = mfma_16x16x32(A, Bf[j], acc[m][j]);
      }
    }
    #pragma unroll
    for (int j = 0; j < 4; ++j) {
      float bv = qkv_b[(1 + (j >> 1)) * 128 + h * 32 + (j & 1) * 16 + r16];
      int dcol = (j & 1) * 16 + r16;
      unsigned short* dst = (j < 2) ? OBK : OBV;
      #pragma unroll
      for (int m = 0; m < 3; ++m)
        #pragma unroll
        for (int rr = 0; rr < 4; ++rr) {
          int tokL = (wid * 3 + m) * 16 + 4 * g + rr;
          dst[tokL * 40 + dcol] = f2bf(acc[m][j][rr] + bv);
        }
    }
  };

  // RST: R7's exact staging transform, reading from OBK/OBV instead of global
  auto RST = [&]() {
    #pragma unroll
    for (int it = 0; it < 12; ++it) {
      int f = it * 256 + tid;
      int kv = f >> 4, cu = f & 15;
      KF[(cu >> 2) * 768 + kv * 4 + (cu & 3)] = *(const unsigned int*)&OBK[kv * 40 + 2 * cu];
      int kv32 = kv & 31;
      int idx = (kv >> 5) * 32 + ((kv32 & 15) >> 2) * 8 + (kv32 >> 4) * 4 + (kv32 & 3);
      unsigned int pk = *(const unsigned int*)&OBV[kv * 40 + 2 * cu];
      VT[(2 * cu) * 200 + idx] = (unsigned short)(pk & 0xffffu);
      VT[(2 * cu + 1) * 200 + idx] = (unsigned short)(pk >> 16);
    }
  };

  // APH: R7 attention compute, verbatim
  auto APH = [&]() {
    for (int kvt2 = 0; kvt2 < 6; ++kvt2) {
      bf16x8 kf0 = __builtin_bit_cast(bf16x8, *(const uint4*)&KF[g * 768 + (kvt2 * 32 + r16) * 4]);
      bf16x8 kf1 = __builtin_bit_cast(bf16x8, *(const uint4*)&KF[g * 768 + (kvt2 * 32 + 16 + r16) * 4]);
      f32x4 zero = f32x4{0.f, 0.f, 0.f, 0.f};
      f32x4 st0[4], st1[4];
      #pragma unroll
      for (int qnt = 0; qnt < 4; ++qnt) {
        st0[qnt] = mfma_16x16x32(kf0, qf[qnt], zero);
        st1[qnt] = mfma_16x16x32(kf1, qf[qnt], zero);
      }
      bf16x8 pf[4];
      #pragma unroll
      for (int qnt = 0; qnt < 4; ++qnt) {
        f32x4 s0 = st0[qnt], s1 = st1[qnt];
        float p[8];
        #pragma unroll
        for (int j = 0; j < 4; ++j) p[j] = __builtin_amdgcn_exp2f(s0[j] * KE);
        #pragma unroll
        for (int j = 0; j < 4; ++j) p[4 + j] = __builtin_amdgcn_exp2f(s1[j] * KE);
        ls[qnt] += ((p[0] + p[1]) + (p[2] + p[3])) + ((p[4] + p[5]) + (p[6] + p[7]));
        uint4 pk4;
        pk4.x = cvt_pk_bf16(p[0], p[1]);
        pk4.y = cvt_pk_bf16(p[2], p[3]);
        pk4.z = cvt_pk_bf16(p[4], p[5]);
        pk4.w = cvt_pk_bf16(p[6], p[7]);
        pf[qnt] = __builtin_bit_cast(bf16x8, pk4);
      }
      #pragma unroll
      for (int dmt = 0; dmt < 2; ++dmt) {
        int d = dmt * 16 + r16;
        bf16x8 vf = __builtin_bit_cast(bf16x8, *(const uint4*)&VT[d * 200 + kvt2 * 32 + g * 8]);
        #pragma unroll
        for (int qnt = 0; qnt < 4; ++qnt)
          oa[dmt][qnt] = mfma_16x16x32(vf, pf[qnt], oa[dmt][qnt]);
      }
    }
  };

  // chunk schedule: GPH -> sync -> RST -> sync -> APH ∥ GPH(next)
  GPH(0);
  __syncthreads();
  RST();
  __syncthreads();
  APH(); GPH(1);
  __syncthreads();
  RST();
  __syncthreads();
  APH(); GPH(2);
  __syncthreads();
  RST();
  __syncthreads();
  APH();

  // epilogue: normalize + write ao (token-major [b][q][128]) [R7-proven]
  #pragma unroll
  for (int qnt = 0; qnt < 4; ++qnt) {
    float l = ls[qnt];
    l += __shfl_xor(l, 16);
    l += __shfl_xor(l, 32);
    float rl = 1.0f / l;
    int q = qb + qnt * 16 + r16;
    #pragma unroll
    for (int dmt = 0; dmt < 2; ++dmt) {
      #pragma unroll
      for (int rr = 0; rr < 4; ++rr) {
        int d = dmt * 16 + 4 * g + rr;
        ao[((size_t)b * 256 + q) * 128 + h * 32 + d] = f2bf(oa[dmt][qnt][rr] * rl);
      }
    }
  }
}

// ---------------- kernel 3: output projection + layout to [B,C,16,16] ----------------
__global__ __launch_bounds__(256) void proj_kernel(
    const unsigned short* __restrict__ ao, const unsigned short* __restrict__ wp,
    const float* __restrict__ proj_b, float* __restrict__ out) {
  __shared__ __align__(16) unsigned int A32[64 * 64];
  const int wg = blockIdx.x;
  const int b = wg >> 2;
  const int mq = wg & 3;
  const int tid = threadIdx.x;
  const int lane = tid & 63;
  const int wid = tid >> 6;
  const int g = lane >> 4;
  const int r16 = lane & 15;

  const unsigned int* asrc = (const unsigned int*)(ao + ((size_t)b * 256 + mq * 64) * 128);
  #pragma unroll
  for (int it = 0; it < 4; ++it) {
    int f = it * 256 + tid;
    int row = f >> 4, q4 = f & 15;
    uint4 v = *(const uint4*)&asrc[row * 64 + q4 * 4];
    *(uint4*)&A32[row * 64 + ((q4 * 4) ^ ((row & 7) << 2))] = v;
  }
  bar_lds();

  f32x4 acc[2][4];
  #pragma unroll
  for (int nt = 0; nt < 2; ++nt)
    #pragma unroll
    for (int mt = 0; mt < 4; ++mt) acc[nt][mt] = f32x4{0.f, 0.f, 0.f, 0.f};

  for (int kt = 0; kt < 4; ++kt) {
    bf16x8 afr[4];
    #pragma unroll
    for (int mt = 0; mt < 4; ++mt) {
      int row = mt * 16 + r16;
      int cub = (kt * 16 + g * 4) ^ ((row & 7) << 2);
      afr[mt] = __builtin_bit_cast(bf16x8, *(const uint4*)&A32[row * 64 + cub]);
    }
    #pragma unroll
    for (int nt = 0; nt < 2; ++nt) {
      int n = wid * 32 + nt * 16 + r16;
      bf16x8 bfr = __builtin_bit_cast(bf16x8, *(const uint4*)(wp + n * 128 + kt * 32 + g * 8));
      #pragma unroll
      for (int mt = 0; mt < 4; ++mt)
        acc[nt][mt] = mfma_16x16x32(afr[mt], bfr, acc[nt][mt]);
    }
  }

  #pragma unroll
  for (int nt = 0; nt < 2; ++nt) {
    int c = wid * 32 + nt * 16 + r16;
    float bv = proj_b[c];
    #pragma unroll
    for (int mt = 0; mt < 4; ++mt) {
      int t0 = mq * 64 + mt * 16 + 4 * g;
      float4 o;
      o.x = acc[nt][mt][0] + bv;
      o.y = acc[nt][mt][1] + bv;
      o.z = acc[nt][mt][2] + bv;
      o.w = acc[nt][mt][3] + bv;
      *(float4*)&out[((size_t)b * 128 + c) * 256 + t0] = o;
    }
  }
}

extern "C" void kernel_launch(void* const* d_in, const int* in_sizes, int n_in,
                              void* d_out, int out_size, void* d_ws, size_t ws_size,
                              hipStream_t stream) {
  const float* x = (const float*)d_in[0];
  const float* qkv_w = (const float*)d_in[1];
  const float* qkv_b = (const float*)d_in[2];
  const float* proj_w = (const float*)d_in[3];
  const float* proj_b = (const float*)d_in[4];
  float* out = (float*)d_out;

  unsigned short* ws16 = (unsigned short*)d_ws;
  unsigned short* wp = ws16;                                   // 16,384
  unsigned short* wq = ws16 + 16384;                           // 49,152
  unsigned short* xtp = ws16 + 65536;                          // 16,777,216
  unsigned short* ap = xtp + (size_t)16777216;                 // 16,777,216
  // total ws requirement: ~67.2 MB

  hipLaunchKernelGGL(wcvt, dim3(192), dim3(256), 0, stream, qkv_w, proj_w, wq, wp);
  hipLaunchKernelGGL(xt_kernel, dim3(512), dim3(256), 0, stream, x, xtp);
  hipLaunchKernelGGL(fused_kernel, dim3(2048), dim3(256), 0, stream, xtp, wq, qkv_b, ap);
  hipLaunchKernelGGL(proj_kernel, dim3(2048), dim3(256), 0, stream, ap, wp, proj_b, out);
}